// Round 7
// baseline (290.334 us; speedup 1.0000x reference)
//
#include <hip/hip_runtime.h>
#include <hip/hip_bf16.h>
#include <math.h>

#define NN 100000
#define NE 1600000
#define FF 128
#define HH 64
#define CC 10
#define GG 128
#define BN_EPS 1e-5f

// bucketed-edge constants
#define BNODES 64               // nodes per bucket (dst>>6)
#define NB 1563                 // ceil(NN/BNODES)
#define PBLK 128                // partition blocks (counting sort)
#define ECHUNK 12500            // NE / PBLK exactly
#define MHIST (NB * PBLK)       // 200064
#define NSCAN 782               // ceil(MHIST/256)
#define SCOL_CAP 2048           // max edges/bucket in LDS (mean 1024, +32 sigma)

typedef short v8bf __attribute__((ext_vector_type(8)));
typedef float v4f  __attribute__((ext_vector_type(4)));

__device__ inline ushort f2b(float x) {
    __hip_bfloat16 h = __float2bfloat16(x);
    return *reinterpret_cast<ushort*>(&h);
}
__device__ inline float b2f(ushort u) {
    return __uint_as_float(((unsigned)u) << 16);
}
__device__ inline float blo(unsigned u) { return __uint_as_float(u << 16); }
__device__ inline float bhi(unsigned u) { return __uint_as_float(u & 0xffff0000u); }

// accumulate one 128-bit chunk (8 bf16 channels) into a[8]
__device__ inline void acc8(float* a, const uint4 r) {
    a[0] += blo(r.x); a[1] += bhi(r.x); a[2] += blo(r.y); a[3] += bhi(r.y);
    a[4] += blo(r.z); a[5] += bhi(r.z); a[6] += blo(r.w); a[7] += bhi(r.w);
}

// ---------------- weight swizzle helper (runs inside edge_hist extra blocks) -------
__device__ inline void sw_one(const float* __restrict__ W, ushort* __restrict__ o,
                              int t, int K) {
    const int lane = t & 63, nt = (t >> 6) & 3, ks = t >> 8;
    const int m = lane & 15, quad = lane >> 4;
#pragma unroll
    for (int j = 0; j < 8; ++j) {
        const int kk = ks * 32 + quad * 8 + j;
        const int cc = nt * 16 + m;
        o[t * 8 + j] = f2b(W[kk * 64 + cc]);
    }
}

// ---------------- dual MFMA GEMM: Yl = X@Wl, Yr = X@Wr (bf16 out) ----------------
template<int K, int TPB, bool AF32>
__global__ __launch_bounds__(256) void gemm_mfma(const void* __restrict__ Xv,
                                                 const ushort* __restrict__ Bl,
                                                 const ushort* __restrict__ Br,
                                                 ushort* __restrict__ Yl,
                                                 ushort* __restrict__ Yr) {
    constexpr int KS = K / 32;
    const int lane  = threadIdx.x & 63;
    const int wave  = threadIdx.x >> 6;
    const int nhalf = wave & 1;
    const int rsub  = wave >> 1;
    const int m = lane & 15, quad = lane >> 4;

    v8bf bl[KS][2], br[KS][2];
#pragma unroll
    for (int ks = 0; ks < KS; ++ks)
#pragma unroll
        for (int nt = 0; nt < 2; ++nt) {
            const int nti = nhalf * 2 + nt;
            bl[ks][nt] = *(const v8bf*)(Bl + ((size_t)(ks * 4 + nti) * 64 + lane) * 8);
            br[ks][nt] = *(const v8bf*)(Br + ((size_t)(ks * 4 + nti) * 64 + lane) * 8);
        }

    for (int it = 0; it < TPB; ++it) {
        const int bt = blockIdx.x * TPB + it;
        const int row0 = bt * 32 + rsub * 16;
        if (row0 >= NN) return;
        const v4f z = {0.f, 0.f, 0.f, 0.f};
        v4f accl[2] = {z, z}, accr[2] = {z, z};
#pragma unroll
        for (int ks = 0; ks < KS; ++ks) {
            v8bf a;
            if (AF32) {
                const float* xrow = (const float*)Xv + (size_t)(row0 + m) * K + quad * 8 + ks * 32;
                const float4 a0 = *(const float4*)(xrow);
                const float4 a1 = *(const float4*)(xrow + 4);
                a[0] = (short)f2b(a0.x); a[1] = (short)f2b(a0.y);
                a[2] = (short)f2b(a0.z); a[3] = (short)f2b(a0.w);
                a[4] = (short)f2b(a1.x); a[5] = (short)f2b(a1.y);
                a[6] = (short)f2b(a1.z); a[7] = (short)f2b(a1.w);
            } else {
                const ushort* xrow = (const ushort*)Xv + (size_t)(row0 + m) * K + quad * 8 + ks * 32;
                a = *(const v8bf*)xrow;
            }
#pragma unroll
            for (int nt = 0; nt < 2; ++nt) {
                accl[nt] = __builtin_amdgcn_mfma_f32_16x16x32_bf16(a, bl[ks][nt], accl[nt], 0, 0, 0);
                accr[nt] = __builtin_amdgcn_mfma_f32_16x16x32_bf16(a, br[ks][nt], accr[nt], 0, 0, 0);
            }
        }
#pragma unroll
        for (int nt = 0; nt < 2; ++nt) {
            const int cc = nhalf * 32 + nt * 16 + m;
#pragma unroll
            for (int r = 0; r < 4; ++r) {
                const size_t off = (size_t)(row0 + quad * 4 + r) * 64 + cc;
                Yl[off] = f2b(accl[nt][r]);
                Yr[off] = f2b(accr[nt][r]);
            }
        }
    }
}

// ---------------- pass A1: per-(block,bucket) histogram + fused prep ----------------
__global__ __launch_bounds__(1024) void edge_hist(const int* __restrict__ dst,
                                                  int* __restrict__ hist,
                                                  const float* __restrict__ W1l,
                                                  const float* __restrict__ W1r,
                                                  const float* __restrict__ W2l,
                                                  const float* __restrict__ W2r,
                                                  ushort* __restrict__ w1ls,
                                                  ushort* __restrict__ w1rs,
                                                  ushort* __restrict__ w2ls,
                                                  ushort* __restrict__ w2rs,
                                                  float* __restrict__ gz) {
    if (blockIdx.x >= PBLK) {
        const int t = threadIdx.x;
        if (blockIdx.x == PBLK) {              // 1024 threads: K=128 swizzles
            sw_one(W1l, w1ls, t, FF);
            sw_one(W1r, w1rs, t, FF);
        } else {
            if (t < 512) {                     // K=64 swizzles
                sw_one(W2l, w2ls, t, HH);
                sw_one(W2r, w2rs, t, HH);
            } else {                           // zero gsum (GG*64) + gcnt (GG)
                for (int i = t - 512; i < GG * 64 + GG; i += 512) gz[i] = 0.f;
            }
        }
        return;
    }
    __shared__ int h[NB];
    for (int i = threadIdx.x; i < NB; i += 1024) h[i] = 0;
    __syncthreads();
    const int e0 = blockIdx.x * ECHUNK;
    for (int e = e0 + threadIdx.x; e < e0 + ECHUNK; e += 1024)
        atomicAdd(&h[dst[e] >> 6], 1);
    __syncthreads();
    for (int i = threadIdx.x; i < NB; i += 1024)
        hist[i * PBLK + blockIdx.x] = h[i];   // bucket-major for the scan
}

// ---------------- pass A2: scan (wave-shuffle scan; boff folded into consumers) -----
__global__ __launch_bounds__(256) void scan_block(const int* __restrict__ cnt,
                                                  int* __restrict__ rp,
                                                  int* __restrict__ bsum) {
    __shared__ int ws[4];
    const int tid = threadIdx.x;
    const int lane = tid & 63, wv = tid >> 6;
    const int i = blockIdx.x * 256 + tid;
    const int v = (i < MHIST) ? cnt[i] : 0;
    int inc = v;
#pragma unroll
    for (int off = 1; off < 64; off <<= 1) {
        int t = __shfl_up(inc, off, 64);
        if (lane >= off) inc += t;
    }
    if (lane == 63) ws[wv] = inc;
    __syncthreads();
    int wbase = 0;
#pragma unroll
    for (int w = 0; w < 4; ++w) wbase += (w < wv) ? ws[w] : 0;
    if (i < MHIST) rp[i] = wbase + inc - v;           // exclusive prefix
    if (tid == 255) bsum[blockIdx.x] = wbase + inc;   // block total
}

// scan of NSCAN block sums: 256 threads x 4 elements each (wave-shuffle scan)
__global__ __launch_bounds__(256) void scan_bsums(const int* __restrict__ bsum,
                                                  int* __restrict__ boff) {
    __shared__ int ws[4];
    const int tid = threadIdx.x;
    const int lane = tid & 63, wv = tid >> 6;
    int v[4];
    int tot = 0;
#pragma unroll
    for (int j = 0; j < 4; ++j) {
        const int idx = tid * 4 + j;
        v[j] = (idx < NSCAN) ? bsum[idx] : 0;
        tot += v[j];
    }
    int inc = tot;
#pragma unroll
    for (int off = 1; off < 64; off <<= 1) {
        int t = __shfl_up(inc, off, 64);
        if (lane >= off) inc += t;
    }
    if (lane == 63) ws[wv] = inc;
    __syncthreads();
    int wbase = 0;
#pragma unroll
    for (int w = 0; w < 4; ++w) wbase += (w < wv) ? ws[w] : 0;
    int run = wbase + inc - tot;   // exclusive base for this thread's 4
#pragma unroll
    for (int j = 0; j < 4; ++j) {
        const int idx = tid * 4 + j;
        if (idx < NSCAN) boff[idx] = run;
        run += v[j];
    }
}

// ---------------- pass A3: LDS counting-sort + near-contiguous scatter ----------
__global__ __launch_bounds__(1024) void edge_scatter(const int* __restrict__ src,
                                                     const int* __restrict__ dst,
                                                     const int* __restrict__ hist,
                                                     const int* __restrict__ goffs,
                                                     const int* __restrict__ boff,
                                                     int* __restrict__ pairs) {
    __shared__ int sv[ECHUNK];      // 50000 B: packed (src<<6)|dstLocal, bucket-sorted
    __shared__ int sd[ECHUNK];      // 50000 B: global destination index
    __shared__ int sfill[NB];       //  6252 B: local fill cursor per bucket
    __shared__ int sdelta[NB];      //  6252 B: global_base - local_start per bucket
    __shared__ int wsum[16];
    const int tid = threadIdx.x;
    const int lane = tid & 63, wv = tid >> 6;
    const int p = blockIdx.x;

    int c0 = 0, c1 = 0, g0 = 0, g1 = 0;
    const int i0 = 2 * tid, i1 = 2 * tid + 1;
    if (i0 < NB) {
        const int idx = i0 * PBLK + p;
        c0 = hist[idx];
        g0 = goffs[idx] + boff[idx >> 8];
    }
    if (i1 < NB) {
        const int idx = i1 * PBLK + p;
        c1 = hist[idx];
        g1 = goffs[idx] + boff[idx >> 8];
    }
    const int tv = c0 + c1;
    int inc = tv;
#pragma unroll
    for (int off = 1; off < 64; off <<= 1) {
        int t = __shfl_up(inc, off, 64);
        if (lane >= off) inc += t;
    }
    if (lane == 63) wsum[wv] = inc;
    __syncthreads();
    int wbase = 0;
#pragma unroll
    for (int w = 0; w < 16; ++w) wbase += (w < wv) ? wsum[w] : 0;
    const int excl = wbase + inc - tv;   // local_start for bucket i0
    if (i0 < NB) { sfill[i0] = excl;      sdelta[i0] = g0 - excl; }
    if (i1 < NB) { sfill[i1] = excl + c0; sdelta[i1] = g1 - (excl + c0); }
    __syncthreads();

    const int e0 = p * ECHUNK;
    for (int e = e0 + tid; e < e0 + ECHUNK; e += 1024) {
        const int s = src[e];
        const int d = dst[e];
        const int b = d >> 6;
        const int local = atomicAdd(&sfill[b], 1);
        sv[local] = (s << 6) | (d & (BNODES - 1));
        sd[local] = local + sdelta[b];
    }
    __syncthreads();

    for (int j = tid; j < ECHUNK; j += 1024) {
        pairs[sd[j]] = sv[j];
    }
}

// ---------------- pass A4: within-bucket dst sort, ONCE for both layers ------------
// Reads the bucket-sorted pairs, sorts by dstLocal (spmm's old phases 1-3),
// writes sorted src ids to scols[] and per-node degrees to degs[].
__global__ __launch_bounds__(256) void bucket_sort(const int* __restrict__ goffs,
                                                   const int* __restrict__ boff,
                                                   const int* __restrict__ pairs,
                                                   int* __restrict__ scols,
                                                   int* __restrict__ degs) {
    __shared__ int scol[SCOL_CAP];
    __shared__ int deg[BNODES];
    __shared__ int loffs[BNODES];
    __shared__ int fill[BNODES];
    const int tid = threadIdx.x;
    const int b = blockIdx.x;

    if (tid < BNODES) { deg[tid] = 0; fill[tid] = 0; }
    __syncthreads();

    const int beg = goffs[b * PBLK] + boff[b >> 1];
    int end = (b == NB - 1) ? NE : goffs[(b + 1) * PBLK] + boff[(b + 1) >> 1];
    if (end - beg > SCOL_CAP) end = beg + SCOL_CAP;

    int pv[8];
    int npv = 0;
    for (int i = beg + tid; i < end; i += 256) {
        const int v = pairs[i];
        pv[npv++] = v;
        atomicAdd(&deg[v & (BNODES - 1)], 1);
    }
    __syncthreads();

    if (tid < BNODES) {
        const int v = deg[tid];
        int inc = v;
#pragma unroll
        for (int s = 1; s < 64; s <<= 1) {
            int t = __shfl_up(inc, s, 64);
            if (tid >= s) inc += t;
        }
        loffs[tid] = inc;
    }
    __syncthreads();

    for (int j = 0; j < npv; ++j) {
        const int v = pv[j];
        const int dl = v & (BNODES - 1);
        const int pos = (loffs[dl] - deg[dl]) + atomicAdd(&fill[dl], 1);
        scol[pos] = v >> 6;
    }
    __syncthreads();

    // coalesced write-out of the sorted bucket + its degree row
    const int ne = end - beg;
    for (int i = tid; i < ne; i += 256) scols[beg + i] = scol[i];
    if (tid < BNODES) degs[b * BNODES + tid] = deg[tid];
}

// ---------------- pass B: gather + fused epilogue (phases 1-3 precomputed) ---------
// 256 threads. Stage the pre-sorted src ids into LDS with a coalesced copy, load
// degree row, tiny wave scan, then the proven round-2 phase-4 gather body.
template<bool POOL>
__global__ __launch_bounds__(256) void spmm_sorted(const int* __restrict__ goffs,
                                                   const int* __restrict__ boff,
                                                   const int* __restrict__ scols,
                                                   const int* __restrict__ degs,
                                                   const ushort* __restrict__ Yl,
                                                   const ushort* __restrict__ Yr,
                                                   const float* __restrict__ bias,
                                                   const float* __restrict__ bng,
                                                   const float* __restrict__ bnb,
                                                   const float* __restrict__ bnm,
                                                   const float* __restrict__ bnv,
                                                   ushort* __restrict__ outp,
                                                   const int* __restrict__ batch,
                                                   float* __restrict__ gsum,
                                                   float* __restrict__ gcnt) {
    __shared__ int scol[SCOL_CAP];      // 8 KB: dst-sorted src ids
    __shared__ int deg_s[BNODES];
    __shared__ int loffs[BNODES];       // inclusive scan of deg
    __shared__ float pbuf[4][64];       // pool partials (POOL only)
    __shared__ float pcnt[4];
    __shared__ int g0s;
    const int tid = threadIdx.x;
    const int b = blockIdx.x;

    if (POOL) {
        pbuf[tid >> 6][tid & 63] = 0.f;
        if (tid < 4) pcnt[tid] = 0.f;
        if (tid == 0) g0s = batch[b * BNODES];
    }

    const int beg = goffs[b * PBLK] + boff[b >> 1];
    int end = (b == NB - 1) ? NE : goffs[(b + 1) * PBLK] + boff[(b + 1) >> 1];
    if (end - beg > SCOL_CAP) end = beg + SCOL_CAP;
    const int ne = end - beg;

    // coalesced stage of pre-sorted src ids (no atomics, no sort)
    for (int i = tid; i < ne; i += 256) scol[i] = scols[beg + i];
    // degree row + wave-0 inclusive scan
    if (tid < BNODES) {
        const int v = degs[b * BNODES + tid];
        deg_s[tid] = v;
        int inc = v;
#pragma unroll
        for (int s = 1; s < 64; s <<= 1) {
            int t = __shfl_up(inc, s, 64);
            if (tid >= s) inc += t;
        }
        loffs[tid] = inc;
    }
    __syncthreads();

    // phase 4: gather + mean + bias + root + BN + ReLU (+ pool or store)
    const int wv = tid >> 6, lane = tid & 63;
    const int grp = lane >> 3, subl = lane & 7;

    float biasj[8], scj[8], mj[8], bbj[8];
#pragma unroll
    for (int j = 0; j < 8; ++j) {
        const int ch = subl * 8 + j;
        biasj[j] = bias[ch];
        scj[j] = bng[ch] * rsqrtf(bnv[ch] + BN_EPS);
        mj[j] = bnm[ch];
        bbj[j] = bnb[ch];
    }

    for (int i = 0; i < 2; ++i) {
        const int nl = wv * 16 + i * 8 + grp;
        const int node = b * BNODES + nl;
        if (node >= NN) continue;
        const int dg = deg_s[nl];
        const int nbeg = loffs[nl] - dg;
        const int nend = nbeg + dg;
        float a[8] = {0.f, 0.f, 0.f, 0.f, 0.f, 0.f, 0.f, 0.f};
        float c[8] = {0.f, 0.f, 0.f, 0.f, 0.f, 0.f, 0.f, 0.f};
        int e = nbeg;
        // 4 loads in flight (proven round-2 body)
        for (; e + 3 < nend; e += 4) {
            const int s0 = scol[e], s1 = scol[e + 1], s2 = scol[e + 2], s3 = scol[e + 3];
            const uint4 r0 = *(const uint4*)(Yl + (size_t)s0 * 64 + subl * 8);
            const uint4 r1 = *(const uint4*)(Yl + (size_t)s1 * 64 + subl * 8);
            const uint4 r2 = *(const uint4*)(Yl + (size_t)s2 * 64 + subl * 8);
            const uint4 r3 = *(const uint4*)(Yl + (size_t)s3 * 64 + subl * 8);
            acc8(a, r0); acc8(c, r1); acc8(a, r2); acc8(c, r3);
        }
        if (e + 1 < nend) {
            const int s0 = scol[e], s1 = scol[e + 1];
            const uint4 r0 = *(const uint4*)(Yl + (size_t)s0 * 64 + subl * 8);
            const uint4 r1 = *(const uint4*)(Yl + (size_t)s1 * 64 + subl * 8);
            acc8(a, r0); acc8(c, r1);
            e += 2;
        }
        if (e < nend) {
            const int s0 = scol[e];
            const uint4 r0 = *(const uint4*)(Yl + (size_t)s0 * 64 + subl * 8);
            acc8(a, r0);
        }
        const float inv = 1.0f / fmaxf((float)dg, 1.0f);
        const uint4 yr = *(const uint4*)(Yr + (size_t)node * 64 + subl * 8);
        float hj[8];
        hj[0] = (a[0] + c[0]) * inv + biasj[0] + blo(yr.x);
        hj[1] = (a[1] + c[1]) * inv + biasj[1] + bhi(yr.x);
        hj[2] = (a[2] + c[2]) * inv + biasj[2] + blo(yr.y);
        hj[3] = (a[3] + c[3]) * inv + biasj[3] + bhi(yr.y);
        hj[4] = (a[4] + c[4]) * inv + biasj[4] + blo(yr.z);
        hj[5] = (a[5] + c[5]) * inv + biasj[5] + bhi(yr.z);
        hj[6] = (a[6] + c[6]) * inv + biasj[6] + blo(yr.w);
        hj[7] = (a[7] + c[7]) * inv + biasj[7] + bhi(yr.w);
        float o[8];
#pragma unroll
        for (int j = 0; j < 8; ++j)
            o[j] = fmaxf((hj[j] - mj[j]) * scj[j] + bbj[j], 0.0f);
        if (!POOL) {
            unsigned ow[4];
#pragma unroll
            for (int j = 0; j < 4; ++j)
                ow[j] = (unsigned)f2b(o[2 * j]) | ((unsigned)f2b(o[2 * j + 1]) << 16);
            uint4 ov;
            ov.x = ow[0]; ov.y = ow[1]; ov.z = ow[2]; ov.w = ow[3];
            *(uint4*)(outp + (size_t)node * 64 + subl * 8) = ov;
        } else {
            const int g = batch[node];
            const int gi = g - g0s;
            if (gi < 4) {
#pragma unroll
                for (int j = 0; j < 8; ++j) atomicAdd(&pbuf[gi][subl * 8 + j], o[j]);
                if (subl == 0) atomicAdd(&pcnt[gi], 1.0f);
            } else {   // span > 4 graphs in one block: direct (rare/never)
#pragma unroll
                for (int j = 0; j < 8; ++j) atomicAdd(&gsum[g * 64 + subl * 8 + j], o[j]);
                if (subl == 0) atomicAdd(&gcnt[g], 1.0f);
            }
        }
    }
    if (POOL) {
        __syncthreads();
        const int q = tid >> 6, ch = tid & 63;
        const int g = g0s + q;
        if (g < GG) {
            const float v = pbuf[q][ch];
            if (v != 0.f) atomicAdd(&gsum[g * 64 + ch], v);
        }
        if (tid < 4) {
            const int gq = g0s + tid;
            if (gq < GG && pcnt[tid] > 0.f) atomicAdd(&gcnt[gq], pcnt[tid]);
        }
    }
}

// ---------------- classifier head ----------------
__global__ __launch_bounds__(64) void head_kernel(const float* __restrict__ gsum,
                                                  const float* __restrict__ gcnt,
                                                  const float* __restrict__ Wc1,
                                                  const float* __restrict__ bc1,
                                                  const float* __restrict__ g3,
                                                  const float* __restrict__ b3,
                                                  const float* __restrict__ m3,
                                                  const float* __restrict__ v3,
                                                  const float* __restrict__ Wc2,
                                                  const float* __restrict__ bc2,
                                                  float* __restrict__ out) {
    __shared__ float sg[64];
    __shared__ float st[64];
    __shared__ float sl[10];
    __shared__ float sls;
    const int b = blockIdx.x;
    const int c = threadIdx.x;
    sg[c] = gsum[b * 64 + c] / fmaxf(gcnt[b], 1.0f);
    __syncthreads();
    float acc = bc1[c];
#pragma unroll
    for (int k = 0; k < 64; ++k) acc += sg[k] * Wc1[k * 64 + c];
    const float sc = g3[c] * rsqrtf(v3[c] + BN_EPS);
    st[c] = fmaxf((acc - m3[c]) * sc + b3[c], 0.0f);
    __syncthreads();
    if (c < CC) {
        float lg = bc2[c];
#pragma unroll
        for (int k = 0; k < 64; ++k) lg += st[k] * Wc2[k * CC + c];
        sl[c] = lg;
    }
    __syncthreads();
    if (c == 0) {
        float mx = sl[0];
        for (int i = 1; i < CC; ++i) mx = fmaxf(mx, sl[i]);
        float s = 0.f;
        for (int i = 0; i < CC; ++i) s += expf(sl[i] - mx);
        sls = mx + logf(s);
    }
    __syncthreads();
    if (c < CC) out[b * CC + c] = sl[c] - sls;
}

extern "C" void kernel_launch(void* const* d_in, const int* in_sizes, int n_in,
                              void* d_out, int out_size, void* d_ws, size_t ws_size,
                              hipStream_t stream) {
    const float* x    = (const float*)d_in[0];
    const int*   ei   = (const int*)d_in[1];
    const int*   batch= (const int*)d_in[2];
    const float* W1l  = (const float*)d_in[3];
    const float* W1r  = (const float*)d_in[4];
    const float* b1   = (const float*)d_in[5];
    const float* W2l  = (const float*)d_in[6];
    const float* W2r  = (const float*)d_in[7];
    const float* b2   = (const float*)d_in[8];
    const float* bn1g = (const float*)d_in[9];
    const float* bn1b = (const float*)d_in[10];
    const float* bn1m = (const float*)d_in[11];
    const float* bn1v = (const float*)d_in[12];
    const float* bn2g = (const float*)d_in[13];
    const float* bn2b = (const float*)d_in[14];
    const float* bn2m = (const float*)d_in[15];
    const float* bn2v = (const float*)d_in[16];
    const float* bn3g = (const float*)d_in[17];
    const float* bn3b = (const float*)d_in[18];
    const float* bn3m = (const float*)d_in[19];
    const float* bn3v = (const float*)d_in[20];
    const float* Wc1  = (const float*)d_in[21];
    const float* bc1  = (const float*)d_in[22];
    const float* Wc2  = (const float*)d_in[23];
    const float* bc2  = (const float*)d_in[24];
    float* out = (float*)d_out;

    const int* src = ei;
    const int* dst = ei + NE;

    // workspace layout (all blocks 16B-aligned)
    char* p = (char*)d_ws;
    ushort* yl   = (ushort*)p;                 p += (size_t)NN * 64 * 2;        // 12.8 MB
    ushort* yr   = (ushort*)p;                 p += (size_t)NN * 64 * 2;        // 12.8 MB
    ushort* hbuf = (ushort*)p;                 p += (size_t)NN * 64 * 2;        // 12.8 MB
    int*    pairs= (int*)p;                    p += (size_t)NE * 4;             // 6.4 MB
    int*    scols= (int*)p;                    p += (size_t)NE * 4;             // 6.4 MB
    int*    degs = (int*)p;                    p += (size_t)NB * BNODES * 4;    // 400 KB
    int*    hist = (int*)p;                    p += (size_t)MHIST * 4;          // 800 KB
    int*    goffs= (int*)p;                    p += (size_t)MHIST * 4;          // 800 KB
    int*    bsum = (int*)p;                    p += 1024 * 4;
    int*    boff = (int*)p;                    p += 1024 * 4;
    ushort* w1ls = (ushort*)p;                 p += (size_t)FF * 64 * 2;
    ushort* w1rs = (ushort*)p;                 p += (size_t)FF * 64 * 2;
    ushort* w2ls = (ushort*)p;                 p += (size_t)HH * 64 * 2;
    ushort* w2rs = (ushort*)p;                 p += (size_t)HH * 64 * 2;
    float* gsum  = (float*)p;                  p += (size_t)GG * 64 * 4;        // gsum+gcnt
    float* gcnt  = gsum + GG * 64;             p += (size_t)GG * 4;             //  contiguous

    // ---- edge counting sort (once, reused by both layers) + fused prep ----
    edge_hist<<<PBLK + 2, 1024, 0, stream>>>(dst, hist, W1l, W1r, W2l, W2r,
                                             w1ls, w1rs, w2ls, w2rs, gsum);
    scan_block<<<NSCAN, 256, 0, stream>>>(hist, goffs, bsum);
    scan_bsums<<<1, 256, 0, stream>>>(bsum, boff);
    edge_scatter<<<PBLK, 1024, 0, stream>>>(src, dst, hist, goffs, boff, pairs);
    bucket_sort<<<NB, 256, 0, stream>>>(goffs, boff, pairs, scols, degs);

    // ---- layer 1 ----
    gemm_mfma<FF, 2, true><<<1563, 256, 0, stream>>>((const void*)x, w1ls, w1rs, yl, yr);
    spmm_sorted<false><<<NB, 256, 0, stream>>>(goffs, boff, scols, degs, yl, yr, b1,
                                               bn1g, bn1b, bn1m, bn1v, hbuf,
                                               batch, gsum, gcnt);

    // ---- layer 2 (pool fused into spmm epilogue; no h write) ----
    gemm_mfma<HH, 2, false><<<1563, 256, 0, stream>>>((const void*)hbuf, w2ls, w2rs, yl, yr);
    spmm_sorted<true><<<NB, 256, 0, stream>>>(goffs, boff, scols, degs, yl, yr, b2,
                                              bn2g, bn2b, bn2m, bn2v, hbuf,
                                              batch, gsum, gcnt);

    // ---- head ----
    head_kernel<<<GG, 64, 0, stream>>>(gsum, gcnt, Wc1, bc1,
                                       bn3g, bn3b, bn3m, bn3v, Wc2, bc2, out);
}

// Round 8
// 280.401 us; speedup vs baseline: 1.0354x; 1.0354x over previous
//
#include <hip/hip_runtime.h>
#include <hip/hip_bf16.h>
#include <math.h>

#define NN 100000
#define NE 1600000
#define FF 128
#define HH 64
#define CC 10
#define GG 128
#define BN_EPS 1e-5f

// bucketed-edge constants
#define BNODES 64               // nodes per bucket (dst>>6)
#define NB 1563                 // ceil(NN/BNODES)
#define PBLK 128                // partition blocks (counting sort)
#define ECHUNK 12500            // NE / PBLK exactly
#define MHIST (NB * PBLK)       // 200064
#define NSCAN 782               // ceil(MHIST/256)
#define SCOL_CAP 2048           // max edges/bucket in LDS (mean 1024, +32 sigma)

typedef short v8bf __attribute__((ext_vector_type(8)));
typedef float v4f  __attribute__((ext_vector_type(4)));
typedef float v2f  __attribute__((ext_vector_type(2)));
typedef unsigned char uchar;

__device__ inline ushort f2b(float x) {
    __hip_bfloat16 h = __float2bfloat16(x);
    return *reinterpret_cast<ushort*>(&h);
}
__device__ inline float b2f(ushort u) {
    return __uint_as_float(((unsigned)u) << 16);
}
__device__ inline float blo(unsigned u) { return __uint_as_float(u << 16); }
__device__ inline float bhi(unsigned u) { return __uint_as_float(u & 0xffff0000u); }

// accumulate one 128-bit chunk (8 bf16 channels) into a[8]
__device__ inline void acc8(float* a, const uint4 r) {
    a[0] += blo(r.x); a[1] += bhi(r.x); a[2] += blo(r.y); a[3] += bhi(r.y);
    a[4] += blo(r.z); a[5] += bhi(r.z); a[6] += blo(r.w); a[7] += bhi(r.w);
}

// accumulate one 64-bit chunk (8 fp8-e4m3 channels) into a[8] via HW cvt (OCP on gfx950)
__device__ inline void accf8(float* a, const uint2 r) {
    v2f p;
    p = __builtin_amdgcn_cvt_pk_f32_fp8((int)r.x, false); a[0] += p[0]; a[1] += p[1];
    p = __builtin_amdgcn_cvt_pk_f32_fp8((int)r.x, true);  a[2] += p[0]; a[3] += p[1];
    p = __builtin_amdgcn_cvt_pk_f32_fp8((int)r.y, false); a[4] += p[0]; a[5] += p[1];
    p = __builtin_amdgcn_cvt_pk_f32_fp8((int)r.y, true);  a[6] += p[0]; a[7] += p[1];
}

// ---------------- weight swizzle helper (runs inside edge_hist extra blocks) -------
__device__ inline void sw_one(const float* __restrict__ W, ushort* __restrict__ o,
                              int t, int K) {
    const int lane = t & 63, nt = (t >> 6) & 3, ks = t >> 8;
    const int m = lane & 15, quad = lane >> 4;
#pragma unroll
    for (int j = 0; j < 8; ++j) {
        const int kk = ks * 32 + quad * 8 + j;
        const int cc = nt * 16 + m;
        o[t * 8 + j] = f2b(W[kk * 64 + cc]);
    }
}

// ---------------- dual MFMA GEMM: Yl = X@Wl (fp8 out), Yr = X@Wr (bf16 out) --------
// Yl feeds the random edge-gather: fp8 e4m3 halves its row to 64B = ONE cache line.
// Yr feeds the per-node (sequential) root term: stays bf16.
template<int K, int TPB, bool AF32>
__global__ __launch_bounds__(256) void gemm_mfma(const void* __restrict__ Xv,
                                                 const ushort* __restrict__ Bl,
                                                 const ushort* __restrict__ Br,
                                                 uchar* __restrict__ Yl8,
                                                 ushort* __restrict__ Yr) {
    constexpr int KS = K / 32;
    const int lane  = threadIdx.x & 63;
    const int wave  = threadIdx.x >> 6;
    const int nhalf = wave & 1;
    const int rsub  = wave >> 1;
    const int m = lane & 15, quad = lane >> 4;

    v8bf bl[KS][2], br[KS][2];
#pragma unroll
    for (int ks = 0; ks < KS; ++ks)
#pragma unroll
        for (int nt = 0; nt < 2; ++nt) {
            const int nti = nhalf * 2 + nt;
            bl[ks][nt] = *(const v8bf*)(Bl + ((size_t)(ks * 4 + nti) * 64 + lane) * 8);
            br[ks][nt] = *(const v8bf*)(Br + ((size_t)(ks * 4 + nti) * 64 + lane) * 8);
        }

    for (int it = 0; it < TPB; ++it) {
        const int bt = blockIdx.x * TPB + it;
        const int row0 = bt * 32 + rsub * 16;
        if (row0 >= NN) return;
        const v4f z = {0.f, 0.f, 0.f, 0.f};
        v4f accl[2] = {z, z}, accr[2] = {z, z};
#pragma unroll
        for (int ks = 0; ks < KS; ++ks) {
            v8bf a;
            if (AF32) {
                const float* xrow = (const float*)Xv + (size_t)(row0 + m) * K + quad * 8 + ks * 32;
                const float4 a0 = *(const float4*)(xrow);
                const float4 a1 = *(const float4*)(xrow + 4);
                a[0] = (short)f2b(a0.x); a[1] = (short)f2b(a0.y);
                a[2] = (short)f2b(a0.z); a[3] = (short)f2b(a0.w);
                a[4] = (short)f2b(a1.x); a[5] = (short)f2b(a1.y);
                a[6] = (short)f2b(a1.z); a[7] = (short)f2b(a1.w);
            } else {
                const ushort* xrow = (const ushort*)Xv + (size_t)(row0 + m) * K + quad * 8 + ks * 32;
                a = *(const v8bf*)xrow;
            }
#pragma unroll
            for (int nt = 0; nt < 2; ++nt) {
                accl[nt] = __builtin_amdgcn_mfma_f32_16x16x32_bf16(a, bl[ks][nt], accl[nt], 0, 0, 0);
                accr[nt] = __builtin_amdgcn_mfma_f32_16x16x32_bf16(a, br[ks][nt], accr[nt], 0, 0, 0);
            }
        }
#pragma unroll
        for (int nt = 0; nt < 2; ++nt) {
            const int cc = nhalf * 32 + nt * 16 + m;
#pragma unroll
            for (int r = 0; r < 4; ++r) {
                const size_t off = (size_t)(row0 + quad * 4 + r) * 64 + cc;
                const int pk = __builtin_amdgcn_cvt_pk_fp8_f32(accl[nt][r], accl[nt][r], 0, false);
                Yl8[off] = (uchar)(pk & 0xFF);
                Yr[off] = f2b(accr[nt][r]);
            }
        }
    }
}

// ---------------- pass A1: per-(block,bucket) histogram + fused prep ----------------
__global__ __launch_bounds__(1024) void edge_hist(const int* __restrict__ dst,
                                                  int* __restrict__ hist,
                                                  const float* __restrict__ W1l,
                                                  const float* __restrict__ W1r,
                                                  const float* __restrict__ W2l,
                                                  const float* __restrict__ W2r,
                                                  ushort* __restrict__ w1ls,
                                                  ushort* __restrict__ w1rs,
                                                  ushort* __restrict__ w2ls,
                                                  ushort* __restrict__ w2rs,
                                                  float* __restrict__ gz) {
    if (blockIdx.x >= PBLK) {
        const int t = threadIdx.x;
        if (blockIdx.x == PBLK) {              // 1024 threads: K=128 swizzles
            sw_one(W1l, w1ls, t, FF);
            sw_one(W1r, w1rs, t, FF);
        } else {
            if (t < 512) {                     // K=64 swizzles
                sw_one(W2l, w2ls, t, HH);
                sw_one(W2r, w2rs, t, HH);
            } else {                           // zero gsum (GG*64) + gcnt (GG)
                for (int i = t - 512; i < GG * 64 + GG; i += 512) gz[i] = 0.f;
            }
        }
        return;
    }
    __shared__ int h[NB];
    for (int i = threadIdx.x; i < NB; i += 1024) h[i] = 0;
    __syncthreads();
    const int e0 = blockIdx.x * ECHUNK;
    for (int e = e0 + threadIdx.x; e < e0 + ECHUNK; e += 1024)
        atomicAdd(&h[dst[e] >> 6], 1);
    __syncthreads();
    for (int i = threadIdx.x; i < NB; i += 1024)
        hist[i * PBLK + blockIdx.x] = h[i];   // bucket-major for the scan
}

// ---------------- pass A2: scan (wave-shuffle scan; boff folded into consumers) -----
__global__ __launch_bounds__(256) void scan_block(const int* __restrict__ cnt,
                                                  int* __restrict__ rp,
                                                  int* __restrict__ bsum) {
    __shared__ int ws[4];
    const int tid = threadIdx.x;
    const int lane = tid & 63, wv = tid >> 6;
    const int i = blockIdx.x * 256 + tid;
    const int v = (i < MHIST) ? cnt[i] : 0;
    int inc = v;
#pragma unroll
    for (int off = 1; off < 64; off <<= 1) {
        int t = __shfl_up(inc, off, 64);
        if (lane >= off) inc += t;
    }
    if (lane == 63) ws[wv] = inc;
    __syncthreads();
    int wbase = 0;
#pragma unroll
    for (int w = 0; w < 4; ++w) wbase += (w < wv) ? ws[w] : 0;
    if (i < MHIST) rp[i] = wbase + inc - v;           // exclusive prefix
    if (tid == 255) bsum[blockIdx.x] = wbase + inc;   // block total
}

// scan of NSCAN block sums: 256 threads x 4 elements each (wave-shuffle scan)
__global__ __launch_bounds__(256) void scan_bsums(const int* __restrict__ bsum,
                                                  int* __restrict__ boff) {
    __shared__ int ws[4];
    const int tid = threadIdx.x;
    const int lane = tid & 63, wv = tid >> 6;
    int v[4];
    int tot = 0;
#pragma unroll
    for (int j = 0; j < 4; ++j) {
        const int idx = tid * 4 + j;
        v[j] = (idx < NSCAN) ? bsum[idx] : 0;
        tot += v[j];
    }
    int inc = tot;
#pragma unroll
    for (int off = 1; off < 64; off <<= 1) {
        int t = __shfl_up(inc, off, 64);
        if (lane >= off) inc += t;
    }
    if (lane == 63) ws[wv] = inc;
    __syncthreads();
    int wbase = 0;
#pragma unroll
    for (int w = 0; w < 4; ++w) wbase += (w < wv) ? ws[w] : 0;
    int run = wbase + inc - tot;   // exclusive base for this thread's 4
#pragma unroll
    for (int j = 0; j < 4; ++j) {
        const int idx = tid * 4 + j;
        if (idx < NSCAN) boff[idx] = run;
        run += v[j];
    }
}

// ---------------- pass A3: LDS counting-sort + near-contiguous scatter ----------
__global__ __launch_bounds__(1024) void edge_scatter(const int* __restrict__ src,
                                                     const int* __restrict__ dst,
                                                     const int* __restrict__ hist,
                                                     const int* __restrict__ goffs,
                                                     const int* __restrict__ boff,
                                                     int* __restrict__ pairs) {
    __shared__ int sv[ECHUNK];      // 50000 B: packed (src<<6)|dstLocal, bucket-sorted
    __shared__ int sd[ECHUNK];      // 50000 B: global destination index
    __shared__ int sfill[NB];       //  6252 B: local fill cursor per bucket
    __shared__ int sdelta[NB];      //  6252 B: global_base - local_start per bucket
    __shared__ int wsum[16];
    const int tid = threadIdx.x;
    const int lane = tid & 63, wv = tid >> 6;
    const int p = blockIdx.x;

    int c0 = 0, c1 = 0, g0 = 0, g1 = 0;
    const int i0 = 2 * tid, i1 = 2 * tid + 1;
    if (i0 < NB) {
        const int idx = i0 * PBLK + p;
        c0 = hist[idx];
        g0 = goffs[idx] + boff[idx >> 8];
    }
    if (i1 < NB) {
        const int idx = i1 * PBLK + p;
        c1 = hist[idx];
        g1 = goffs[idx] + boff[idx >> 8];
    }
    const int tv = c0 + c1;
    int inc = tv;
#pragma unroll
    for (int off = 1; off < 64; off <<= 1) {
        int t = __shfl_up(inc, off, 64);
        if (lane >= off) inc += t;
    }
    if (lane == 63) wsum[wv] = inc;
    __syncthreads();
    int wbase = 0;
#pragma unroll
    for (int w = 0; w < 16; ++w) wbase += (w < wv) ? wsum[w] : 0;
    const int excl = wbase + inc - tv;   // local_start for bucket i0
    if (i0 < NB) { sfill[i0] = excl;      sdelta[i0] = g0 - excl; }
    if (i1 < NB) { sfill[i1] = excl + c0; sdelta[i1] = g1 - (excl + c0); }
    __syncthreads();

    const int e0 = p * ECHUNK;
    for (int e = e0 + tid; e < e0 + ECHUNK; e += 1024) {
        const int s = src[e];
        const int d = dst[e];
        const int b = d >> 6;
        const int local = atomicAdd(&sfill[b], 1);
        sv[local] = (s << 6) | (d & (BNODES - 1));
        sd[local] = local + sdelta[b];
    }
    __syncthreads();

    for (int j = tid; j < ECHUNK; j += 1024) {
        pairs[sd[j]] = sv[j];
    }
}

// ---------------- pass A4: within-bucket dst sort, ONCE for both layers ------------
__global__ __launch_bounds__(256) void bucket_sort(const int* __restrict__ goffs,
                                                   const int* __restrict__ boff,
                                                   const int* __restrict__ pairs,
                                                   int* __restrict__ scols,
                                                   int* __restrict__ degs) {
    __shared__ int scol[SCOL_CAP];
    __shared__ int deg[BNODES];
    __shared__ int loffs[BNODES];
    __shared__ int fill[BNODES];
    const int tid = threadIdx.x;
    const int b = blockIdx.x;

    if (tid < BNODES) { deg[tid] = 0; fill[tid] = 0; }
    __syncthreads();

    const int beg = goffs[b * PBLK] + boff[b >> 1];
    int end = (b == NB - 1) ? NE : goffs[(b + 1) * PBLK] + boff[(b + 1) >> 1];
    if (end - beg > SCOL_CAP) end = beg + SCOL_CAP;

    int pv[8];
    int npv = 0;
    for (int i = beg + tid; i < end; i += 256) {
        const int v = pairs[i];
        pv[npv++] = v;
        atomicAdd(&deg[v & (BNODES - 1)], 1);
    }
    __syncthreads();

    if (tid < BNODES) {
        const int v = deg[tid];
        int inc = v;
#pragma unroll
        for (int s = 1; s < 64; s <<= 1) {
            int t = __shfl_up(inc, s, 64);
            if (tid >= s) inc += t;
        }
        loffs[tid] = inc;
    }
    __syncthreads();

    for (int j = 0; j < npv; ++j) {
        const int v = pv[j];
        const int dl = v & (BNODES - 1);
        const int pos = (loffs[dl] - deg[dl]) + atomicAdd(&fill[dl], 1);
        scol[pos] = v >> 6;
    }
    __syncthreads();

    // coalesced write-out of the sorted bucket + its degree row
    const int ne = end - beg;
    for (int i = tid; i < ne; i += 256) scols[beg + i] = scol[i];
    if (tid < BNODES) degs[b * BNODES + tid] = deg[tid];
}

// ---------------- pass B: fp8 gather + fused epilogue (phases 1-3 precomputed) -----
// Each edge now reads ONE 64B line (fp8 row) instead of two bf16 lines. Decode via
// v_cvt_pk_f32_fp8 (2 ch/instr). Everything else identical to the proven body.
template<bool POOL>
__global__ __launch_bounds__(256) void spmm_sorted(const int* __restrict__ goffs,
                                                   const int* __restrict__ boff,
                                                   const int* __restrict__ scols,
                                                   const int* __restrict__ degs,
                                                   const uchar* __restrict__ Yl8,
                                                   const ushort* __restrict__ Yr,
                                                   const float* __restrict__ bias,
                                                   const float* __restrict__ bng,
                                                   const float* __restrict__ bnb,
                                                   const float* __restrict__ bnm,
                                                   const float* __restrict__ bnv,
                                                   ushort* __restrict__ outp,
                                                   const int* __restrict__ batch,
                                                   float* __restrict__ gsum,
                                                   float* __restrict__ gcnt) {
    __shared__ int scol[SCOL_CAP];      // 8 KB: dst-sorted src ids
    __shared__ int deg_s[BNODES];
    __shared__ int loffs[BNODES];       // inclusive scan of deg
    __shared__ float pbuf[4][64];       // pool partials (POOL only)
    __shared__ float pcnt[4];
    __shared__ int g0s;
    const int tid = threadIdx.x;
    const int b = blockIdx.x;

    if (POOL) {
        pbuf[tid >> 6][tid & 63] = 0.f;
        if (tid < 4) pcnt[tid] = 0.f;
        if (tid == 0) g0s = batch[b * BNODES];
    }

    const int beg = goffs[b * PBLK] + boff[b >> 1];
    int end = (b == NB - 1) ? NE : goffs[(b + 1) * PBLK] + boff[(b + 1) >> 1];
    if (end - beg > SCOL_CAP) end = beg + SCOL_CAP;
    const int ne = end - beg;

    // coalesced stage of pre-sorted src ids (no atomics, no sort)
    for (int i = tid; i < ne; i += 256) scol[i] = scols[beg + i];
    // degree row + wave-0 inclusive scan
    if (tid < BNODES) {
        const int v = degs[b * BNODES + tid];
        deg_s[tid] = v;
        int inc = v;
#pragma unroll
        for (int s = 1; s < 64; s <<= 1) {
            int t = __shfl_up(inc, s, 64);
            if (tid >= s) inc += t;
        }
        loffs[tid] = inc;
    }
    __syncthreads();

    // phase 4: gather + mean + bias + root + BN + ReLU (+ pool or store)
    const int wv = tid >> 6, lane = tid & 63;
    const int grp = lane >> 3, subl = lane & 7;

    float biasj[8], scj[8], mj[8], bbj[8];
#pragma unroll
    for (int j = 0; j < 8; ++j) {
        const int ch = subl * 8 + j;
        biasj[j] = bias[ch];
        scj[j] = bng[ch] * rsqrtf(bnv[ch] + BN_EPS);
        mj[j] = bnm[ch];
        bbj[j] = bnb[ch];
    }

    for (int i = 0; i < 2; ++i) {
        const int nl = wv * 16 + i * 8 + grp;
        const int node = b * BNODES + nl;
        if (node >= NN) continue;
        const int dg = deg_s[nl];
        const int nbeg = loffs[nl] - dg;
        const int nend = nbeg + dg;
        float a[8] = {0.f, 0.f, 0.f, 0.f, 0.f, 0.f, 0.f, 0.f};
        float c[8] = {0.f, 0.f, 0.f, 0.f, 0.f, 0.f, 0.f, 0.f};
        int e = nbeg;
        // 4 loads in flight (proven round-2 body; now uint2 = one line per edge)
        for (; e + 3 < nend; e += 4) {
            const int s0 = scol[e], s1 = scol[e + 1], s2 = scol[e + 2], s3 = scol[e + 3];
            const uint2 r0 = *(const uint2*)(Yl8 + (size_t)s0 * 64 + subl * 8);
            const uint2 r1 = *(const uint2*)(Yl8 + (size_t)s1 * 64 + subl * 8);
            const uint2 r2 = *(const uint2*)(Yl8 + (size_t)s2 * 64 + subl * 8);
            const uint2 r3 = *(const uint2*)(Yl8 + (size_t)s3 * 64 + subl * 8);
            accf8(a, r0); accf8(c, r1); accf8(a, r2); accf8(c, r3);
        }
        if (e + 1 < nend) {
            const int s0 = scol[e], s1 = scol[e + 1];
            const uint2 r0 = *(const uint2*)(Yl8 + (size_t)s0 * 64 + subl * 8);
            const uint2 r1 = *(const uint2*)(Yl8 + (size_t)s1 * 64 + subl * 8);
            accf8(a, r0); accf8(c, r1);
            e += 2;
        }
        if (e < nend) {
            const int s0 = scol[e];
            const uint2 r0 = *(const uint2*)(Yl8 + (size_t)s0 * 64 + subl * 8);
            accf8(a, r0);
        }
        const float inv = 1.0f / fmaxf((float)dg, 1.0f);
        const uint4 yr = *(const uint4*)(Yr + (size_t)node * 64 + subl * 8);
        float hj[8];
        hj[0] = (a[0] + c[0]) * inv + biasj[0] + blo(yr.x);
        hj[1] = (a[1] + c[1]) * inv + biasj[1] + bhi(yr.x);
        hj[2] = (a[2] + c[2]) * inv + biasj[2] + blo(yr.y);
        hj[3] = (a[3] + c[3]) * inv + biasj[3] + bhi(yr.y);
        hj[4] = (a[4] + c[4]) * inv + biasj[4] + blo(yr.z);
        hj[5] = (a[5] + c[5]) * inv + biasj[5] + bhi(yr.z);
        hj[6] = (a[6] + c[6]) * inv + biasj[6] + blo(yr.w);
        hj[7] = (a[7] + c[7]) * inv + biasj[7] + bhi(yr.w);
        float o[8];
#pragma unroll
        for (int j = 0; j < 8; ++j)
            o[j] = fmaxf((hj[j] - mj[j]) * scj[j] + bbj[j], 0.0f);
        if (!POOL) {
            unsigned ow[4];
#pragma unroll
            for (int j = 0; j < 4; ++j)
                ow[j] = (unsigned)f2b(o[2 * j]) | ((unsigned)f2b(o[2 * j + 1]) << 16);
            uint4 ov;
            ov.x = ow[0]; ov.y = ow[1]; ov.z = ow[2]; ov.w = ow[3];
            *(uint4*)(outp + (size_t)node * 64 + subl * 8) = ov;
        } else {
            const int g = batch[node];
            const int gi = g - g0s;
            if (gi < 4) {
#pragma unroll
                for (int j = 0; j < 8; ++j) atomicAdd(&pbuf[gi][subl * 8 + j], o[j]);
                if (subl == 0) atomicAdd(&pcnt[gi], 1.0f);
            } else {   // span > 4 graphs in one block: direct (rare/never)
#pragma unroll
                for (int j = 0; j < 8; ++j) atomicAdd(&gsum[g * 64 + subl * 8 + j], o[j]);
                if (subl == 0) atomicAdd(&gcnt[g], 1.0f);
            }
        }
    }
    if (POOL) {
        __syncthreads();
        const int q = tid >> 6, ch = tid & 63;
        const int g = g0s + q;
        if (g < GG) {
            const float v = pbuf[q][ch];
            if (v != 0.f) atomicAdd(&gsum[g * 64 + ch], v);
        }
        if (tid < 4) {
            const int gq = g0s + tid;
            if (gq < GG && pcnt[tid] > 0.f) atomicAdd(&gcnt[gq], pcnt[tid]);
        }
    }
}

// ---------------- classifier head ----------------
__global__ __launch_bounds__(64) void head_kernel(const float* __restrict__ gsum,
                                                  const float* __restrict__ gcnt,
                                                  const float* __restrict__ Wc1,
                                                  const float* __restrict__ bc1,
                                                  const float* __restrict__ g3,
                                                  const float* __restrict__ b3,
                                                  const float* __restrict__ m3,
                                                  const float* __restrict__ v3,
                                                  const float* __restrict__ Wc2,
                                                  const float* __restrict__ bc2,
                                                  float* __restrict__ out) {
    __shared__ float sg[64];
    __shared__ float st[64];
    __shared__ float sl[10];
    __shared__ float sls;
    const int b = blockIdx.x;
    const int c = threadIdx.x;
    sg[c] = gsum[b * 64 + c] / fmaxf(gcnt[b], 1.0f);
    __syncthreads();
    float acc = bc1[c];
#pragma unroll
    for (int k = 0; k < 64; ++k) acc += sg[k] * Wc1[k * 64 + c];
    const float sc = g3[c] * rsqrtf(v3[c] + BN_EPS);
    st[c] = fmaxf((acc - m3[c]) * sc + b3[c], 0.0f);
    __syncthreads();
    if (c < CC) {
        float lg = bc2[c];
#pragma unroll
        for (int k = 0; k < 64; ++k) lg += st[k] * Wc2[k * CC + c];
        sl[c] = lg;
    }
    __syncthreads();
    if (c == 0) {
        float mx = sl[0];
        for (int i = 1; i < CC; ++i) mx = fmaxf(mx, sl[i]);
        float s = 0.f;
        for (int i = 0; i < CC; ++i) s += expf(sl[i] - mx);
        sls = mx + logf(s);
    }
    __syncthreads();
    if (c < CC) out[b * CC + c] = sl[c] - sls;
}

extern "C" void kernel_launch(void* const* d_in, const int* in_sizes, int n_in,
                              void* d_out, int out_size, void* d_ws, size_t ws_size,
                              hipStream_t stream) {
    const float* x    = (const float*)d_in[0];
    const int*   ei   = (const int*)d_in[1];
    const int*   batch= (const int*)d_in[2];
    const float* W1l  = (const float*)d_in[3];
    const float* W1r  = (const float*)d_in[4];
    const float* b1   = (const float*)d_in[5];
    const float* W2l  = (const float*)d_in[6];
    const float* W2r  = (const float*)d_in[7];
    const float* b2   = (const float*)d_in[8];
    const float* bn1g = (const float*)d_in[9];
    const float* bn1b = (const float*)d_in[10];
    const float* bn1m = (const float*)d_in[11];
    const float* bn1v = (const float*)d_in[12];
    const float* bn2g = (const float*)d_in[13];
    const float* bn2b = (const float*)d_in[14];
    const float* bn2m = (const float*)d_in[15];
    const float* bn2v = (const float*)d_in[16];
    const float* bn3g = (const float*)d_in[17];
    const float* bn3b = (const float*)d_in[18];
    const float* bn3m = (const float*)d_in[19];
    const float* bn3v = (const float*)d_in[20];
    const float* Wc1  = (const float*)d_in[21];
    const float* bc1  = (const float*)d_in[22];
    const float* Wc2  = (const float*)d_in[23];
    const float* bc2  = (const float*)d_in[24];
    float* out = (float*)d_out;

    const int* src = ei;
    const int* dst = ei + NE;

    // workspace layout (all blocks 16B-aligned)
    char* p = (char*)d_ws;
    uchar*  yl8  = (uchar*)p;                  p += (size_t)NN * 64;            // 6.4 MB (fp8)
    ushort* yr   = (ushort*)p;                 p += (size_t)NN * 64 * 2;        // 12.8 MB
    ushort* hbuf = (ushort*)p;                 p += (size_t)NN * 64 * 2;        // 12.8 MB
    int*    pairs= (int*)p;                    p += (size_t)NE * 4;             // 6.4 MB
    int*    scols= (int*)p;                    p += (size_t)NE * 4;             // 6.4 MB
    int*    degs = (int*)p;                    p += (size_t)NB * BNODES * 4;    // 400 KB
    int*    hist = (int*)p;                    p += (size_t)MHIST * 4;          // 800 KB
    int*    goffs= (int*)p;                    p += (size_t)MHIST * 4;          // 800 KB
    int*    bsum = (int*)p;                    p += 1024 * 4;
    int*    boff = (int*)p;                    p += 1024 * 4;
    ushort* w1ls = (ushort*)p;                 p += (size_t)FF * 64 * 2;
    ushort* w1rs = (ushort*)p;                 p += (size_t)FF * 64 * 2;
    ushort* w2ls = (ushort*)p;                 p += (size_t)HH * 64 * 2;
    ushort* w2rs = (ushort*)p;                 p += (size_t)HH * 64 * 2;
    float* gsum  = (float*)p;                  p += (size_t)GG * 64 * 4;        // gsum+gcnt
    float* gcnt  = gsum + GG * 64;             p += (size_t)GG * 4;             //  contiguous

    // ---- edge counting sort (once, reused by both layers) + fused prep ----
    edge_hist<<<PBLK + 2, 1024, 0, stream>>>(dst, hist, W1l, W1r, W2l, W2r,
                                             w1ls, w1rs, w2ls, w2rs, gsum);
    scan_block<<<NSCAN, 256, 0, stream>>>(hist, goffs, bsum);
    scan_bsums<<<1, 256, 0, stream>>>(bsum, boff);
    edge_scatter<<<PBLK, 1024, 0, stream>>>(src, dst, hist, goffs, boff, pairs);
    bucket_sort<<<NB, 256, 0, stream>>>(goffs, boff, pairs, scols, degs);

    // ---- layer 1 ----
    gemm_mfma<FF, 2, true><<<1563, 256, 0, stream>>>((const void*)x, w1ls, w1rs, yl8, yr);
    spmm_sorted<false><<<NB, 256, 0, stream>>>(goffs, boff, scols, degs, yl8, yr, b1,
                                               bn1g, bn1b, bn1m, bn1v, hbuf,
                                               batch, gsum, gcnt);

    // ---- layer 2 (pool fused into spmm epilogue; no h write) ----
    gemm_mfma<HH, 2, false><<<1563, 256, 0, stream>>>((const void*)hbuf, w2ls, w2rs, yl8, yr);
    spmm_sorted<true><<<NB, 256, 0, stream>>>(goffs, boff, scols, degs, yl8, yr, b2,
                                              bn2g, bn2b, bn2m, bn2v, hbuf,
                                              batch, gsum, gcnt);

    // ---- head ----
    head_kernel<<<GG, 64, 0, stream>>>(gsum, gcnt, Wc1, bc1,
                                       bn3g, bn3b, bn3m, bn3v, Wc2, bc2, out);
}

// Round 9
// 279.942 us; speedup vs baseline: 1.0371x; 1.0016x over previous
//
#include <hip/hip_runtime.h>
#include <hip/hip_bf16.h>
#include <math.h>

#define NN 100000
#define NE 1600000
#define FF 128
#define HH 64
#define CC 10
#define GG 128
#define BN_EPS 1e-5f

// bucketed-edge constants
#define BNODES 64               // nodes per bucket (dst>>6)
#define NB 1563                 // ceil(NN/BNODES)
#define PBLK 128                // partition blocks (counting sort)
#define ECHUNK 12500            // NE / PBLK exactly
#define MHIST (NB * PBLK)       // 200064
#define NSCAN 782               // ceil(MHIST/256)
#define SCOL_CAP 2048           // max edges/bucket in LDS (mean 1024, +32 sigma)

typedef short v8bf __attribute__((ext_vector_type(8)));
typedef float v4f  __attribute__((ext_vector_type(4)));
typedef float v2f  __attribute__((ext_vector_type(2)));
typedef unsigned char uchar;

__device__ inline ushort f2b(float x) {
    __hip_bfloat16 h = __float2bfloat16(x);
    return *reinterpret_cast<ushort*>(&h);
}
__device__ inline float b2f(ushort u) {
    return __uint_as_float(((unsigned)u) << 16);
}
__device__ inline float blo(unsigned u) { return __uint_as_float(u << 16); }
__device__ inline float bhi(unsigned u) { return __uint_as_float(u & 0xffff0000u); }

// decode 16 fp8-e4m3 (uint4) and accumulate into a[16] via HW cvt (OCP on gfx950)
__device__ inline void accf8x16(float* a, const uint4 r) {
    v2f p;
    p = __builtin_amdgcn_cvt_pk_f32_fp8((int)r.x, false); a[0] += p[0];  a[1] += p[1];
    p = __builtin_amdgcn_cvt_pk_f32_fp8((int)r.x, true);  a[2] += p[0];  a[3] += p[1];
    p = __builtin_amdgcn_cvt_pk_f32_fp8((int)r.y, false); a[4] += p[0];  a[5] += p[1];
    p = __builtin_amdgcn_cvt_pk_f32_fp8((int)r.y, true);  a[6] += p[0];  a[7] += p[1];
    p = __builtin_amdgcn_cvt_pk_f32_fp8((int)r.z, false); a[8] += p[0];  a[9] += p[1];
    p = __builtin_amdgcn_cvt_pk_f32_fp8((int)r.z, true);  a[10] += p[0]; a[11] += p[1];
    p = __builtin_amdgcn_cvt_pk_f32_fp8((int)r.w, false); a[12] += p[0]; a[13] += p[1];
    p = __builtin_amdgcn_cvt_pk_f32_fp8((int)r.w, true);  a[14] += p[0]; a[15] += p[1];
}

// ---------------- weight swizzle helper (runs inside edge_hist extra blocks) -------
__device__ inline void sw_one(const float* __restrict__ W, ushort* __restrict__ o,
                              int t, int K) {
    const int lane = t & 63, nt = (t >> 6) & 3, ks = t >> 8;
    const int m = lane & 15, quad = lane >> 4;
#pragma unroll
    for (int j = 0; j < 8; ++j) {
        const int kk = ks * 32 + quad * 8 + j;
        const int cc = nt * 16 + m;
        o[t * 8 + j] = f2b(W[kk * 64 + cc]);
    }
}

// ---------------- dual MFMA GEMM: Yl = X@Wl (fp8 out), Yr = X@Wr (bf16 out) --------
template<int K, int TPB, bool AF32>
__global__ __launch_bounds__(256) void gemm_mfma(const void* __restrict__ Xv,
                                                 const ushort* __restrict__ Bl,
                                                 const ushort* __restrict__ Br,
                                                 uchar* __restrict__ Yl8,
                                                 ushort* __restrict__ Yr) {
    constexpr int KS = K / 32;
    const int lane  = threadIdx.x & 63;
    const int wave  = threadIdx.x >> 6;
    const int nhalf = wave & 1;
    const int rsub  = wave >> 1;
    const int m = lane & 15, quad = lane >> 4;

    v8bf bl[KS][2], br[KS][2];
#pragma unroll
    for (int ks = 0; ks < KS; ++ks)
#pragma unroll
        for (int nt = 0; nt < 2; ++nt) {
            const int nti = nhalf * 2 + nt;
            bl[ks][nt] = *(const v8bf*)(Bl + ((size_t)(ks * 4 + nti) * 64 + lane) * 8);
            br[ks][nt] = *(const v8bf*)(Br + ((size_t)(ks * 4 + nti) * 64 + lane) * 8);
        }

    for (int it = 0; it < TPB; ++it) {
        const int bt = blockIdx.x * TPB + it;
        const int row0 = bt * 32 + rsub * 16;
        if (row0 >= NN) return;
        const v4f z = {0.f, 0.f, 0.f, 0.f};
        v4f accl[2] = {z, z}, accr[2] = {z, z};
#pragma unroll
        for (int ks = 0; ks < KS; ++ks) {
            v8bf a;
            if (AF32) {
                const float* xrow = (const float*)Xv + (size_t)(row0 + m) * K + quad * 8 + ks * 32;
                const float4 a0 = *(const float4*)(xrow);
                const float4 a1 = *(const float4*)(xrow + 4);
                a[0] = (short)f2b(a0.x); a[1] = (short)f2b(a0.y);
                a[2] = (short)f2b(a0.z); a[3] = (short)f2b(a0.w);
                a[4] = (short)f2b(a1.x); a[5] = (short)f2b(a1.y);
                a[6] = (short)f2b(a1.z); a[7] = (short)f2b(a1.w);
            } else {
                const ushort* xrow = (const ushort*)Xv + (size_t)(row0 + m) * K + quad * 8 + ks * 32;
                a = *(const v8bf*)xrow;
            }
#pragma unroll
            for (int nt = 0; nt < 2; ++nt) {
                accl[nt] = __builtin_amdgcn_mfma_f32_16x16x32_bf16(a, bl[ks][nt], accl[nt], 0, 0, 0);
                accr[nt] = __builtin_amdgcn_mfma_f32_16x16x32_bf16(a, br[ks][nt], accr[nt], 0, 0, 0);
            }
        }
#pragma unroll
        for (int nt = 0; nt < 2; ++nt) {
            const int cc = nhalf * 32 + nt * 16 + m;
#pragma unroll
            for (int r = 0; r < 4; ++r) {
                const size_t off = (size_t)(row0 + quad * 4 + r) * 64 + cc;
                const int pk = __builtin_amdgcn_cvt_pk_fp8_f32(accl[nt][r], accl[nt][r], 0, false);
                Yl8[off] = (uchar)(pk & 0xFF);
                Yr[off] = f2b(accr[nt][r]);
            }
        }
    }
}

// ---------------- pass A1: per-(block,bucket) histogram + fused prep ----------------
__global__ __launch_bounds__(1024) void edge_hist(const int* __restrict__ dst,
                                                  int* __restrict__ hist,
                                                  const float* __restrict__ W1l,
                                                  const float* __restrict__ W1r,
                                                  const float* __restrict__ W2l,
                                                  const float* __restrict__ W2r,
                                                  ushort* __restrict__ w1ls,
                                                  ushort* __restrict__ w1rs,
                                                  ushort* __restrict__ w2ls,
                                                  ushort* __restrict__ w2rs,
                                                  float* __restrict__ gz) {
    if (blockIdx.x >= PBLK) {
        const int t = threadIdx.x;
        if (blockIdx.x == PBLK) {              // 1024 threads: K=128 swizzles
            sw_one(W1l, w1ls, t, FF);
            sw_one(W1r, w1rs, t, FF);
        } else {
            if (t < 512) {                     // K=64 swizzles
                sw_one(W2l, w2ls, t, HH);
                sw_one(W2r, w2rs, t, HH);
            } else {                           // zero gsum (GG*64) + gcnt (GG)
                for (int i = t - 512; i < GG * 64 + GG; i += 512) gz[i] = 0.f;
            }
        }
        return;
    }
    __shared__ int h[NB];
    for (int i = threadIdx.x; i < NB; i += 1024) h[i] = 0;
    __syncthreads();
    const int e0 = blockIdx.x * ECHUNK;
    for (int e = e0 + threadIdx.x; e < e0 + ECHUNK; e += 1024)
        atomicAdd(&h[dst[e] >> 6], 1);
    __syncthreads();
    for (int i = threadIdx.x; i < NB; i += 1024)
        hist[i * PBLK + blockIdx.x] = h[i];   // bucket-major for the scan
}

// ---------------- pass A2: scan (wave-shuffle scan; boff folded into consumers) -----
__global__ __launch_bounds__(256) void scan_block(const int* __restrict__ cnt,
                                                  int* __restrict__ rp,
                                                  int* __restrict__ bsum) {
    __shared__ int ws[4];
    const int tid = threadIdx.x;
    const int lane = tid & 63, wv = tid >> 6;
    const int i = blockIdx.x * 256 + tid;
    const int v = (i < MHIST) ? cnt[i] : 0;
    int inc = v;
#pragma unroll
    for (int off = 1; off < 64; off <<= 1) {
        int t = __shfl_up(inc, off, 64);
        if (lane >= off) inc += t;
    }
    if (lane == 63) ws[wv] = inc;
    __syncthreads();
    int wbase = 0;
#pragma unroll
    for (int w = 0; w < 4; ++w) wbase += (w < wv) ? ws[w] : 0;
    if (i < MHIST) rp[i] = wbase + inc - v;           // exclusive prefix
    if (tid == 255) bsum[blockIdx.x] = wbase + inc;   // block total
}

// scan of NSCAN block sums: 256 threads x 4 elements each (wave-shuffle scan)
__global__ __launch_bounds__(256) void scan_bsums(const int* __restrict__ bsum,
                                                  int* __restrict__ boff) {
    __shared__ int ws[4];
    const int tid = threadIdx.x;
    const int lane = tid & 63, wv = tid >> 6;
    int v[4];
    int tot = 0;
#pragma unroll
    for (int j = 0; j < 4; ++j) {
        const int idx = tid * 4 + j;
        v[j] = (idx < NSCAN) ? bsum[idx] : 0;
        tot += v[j];
    }
    int inc = tot;
#pragma unroll
    for (int off = 1; off < 64; off <<= 1) {
        int t = __shfl_up(inc, off, 64);
        if (lane >= off) inc += t;
    }
    if (lane == 63) ws[wv] = inc;
    __syncthreads();
    int wbase = 0;
#pragma unroll
    for (int w = 0; w < 4; ++w) wbase += (w < wv) ? ws[w] : 0;
    int run = wbase + inc - tot;   // exclusive base for this thread's 4
#pragma unroll
    for (int j = 0; j < 4; ++j) {
        const int idx = tid * 4 + j;
        if (idx < NSCAN) boff[idx] = run;
        run += v[j];
    }
}

// ---------------- pass A3: LDS counting-sort + near-contiguous scatter ----------
__global__ __launch_bounds__(1024) void edge_scatter(const int* __restrict__ src,
                                                     const int* __restrict__ dst,
                                                     const int* __restrict__ hist,
                                                     const int* __restrict__ goffs,
                                                     const int* __restrict__ boff,
                                                     int* __restrict__ pairs) {
    __shared__ int sv[ECHUNK];      // 50000 B: packed (src<<6)|dstLocal, bucket-sorted
    __shared__ int sd[ECHUNK];      // 50000 B: global destination index
    __shared__ int sfill[NB];       //  6252 B: local fill cursor per bucket
    __shared__ int sdelta[NB];      //  6252 B: global_base - local_start per bucket
    __shared__ int wsum[16];
    const int tid = threadIdx.x;
    const int lane = tid & 63, wv = tid >> 6;
    const int p = blockIdx.x;

    int c0 = 0, c1 = 0, g0 = 0, g1 = 0;
    const int i0 = 2 * tid, i1 = 2 * tid + 1;
    if (i0 < NB) {
        const int idx = i0 * PBLK + p;
        c0 = hist[idx];
        g0 = goffs[idx] + boff[idx >> 8];
    }
    if (i1 < NB) {
        const int idx = i1 * PBLK + p;
        c1 = hist[idx];
        g1 = goffs[idx] + boff[idx >> 8];
    }
    const int tv = c0 + c1;
    int inc = tv;
#pragma unroll
    for (int off = 1; off < 64; off <<= 1) {
        int t = __shfl_up(inc, off, 64);
        if (lane >= off) inc += t;
    }
    if (lane == 63) wsum[wv] = inc;
    __syncthreads();
    int wbase = 0;
#pragma unroll
    for (int w = 0; w < 16; ++w) wbase += (w < wv) ? wsum[w] : 0;
    const int excl = wbase + inc - tv;   // local_start for bucket i0
    if (i0 < NB) { sfill[i0] = excl;      sdelta[i0] = g0 - excl; }
    if (i1 < NB) { sfill[i1] = excl + c0; sdelta[i1] = g1 - (excl + c0); }
    __syncthreads();

    const int e0 = p * ECHUNK;
    for (int e = e0 + tid; e < e0 + ECHUNK; e += 1024) {
        const int s = src[e];
        const int d = dst[e];
        const int b = d >> 6;
        const int local = atomicAdd(&sfill[b], 1);
        sv[local] = (s << 6) | (d & (BNODES - 1));
        sd[local] = local + sdelta[b];
    }
    __syncthreads();

    for (int j = tid; j < ECHUNK; j += 1024) {
        pairs[sd[j]] = sv[j];
    }
}

// ---------------- pass A4: within-bucket dst sort, ONCE for both layers ------------
__global__ __launch_bounds__(256) void bucket_sort(const int* __restrict__ goffs,
                                                   const int* __restrict__ boff,
                                                   const int* __restrict__ pairs,
                                                   int* __restrict__ scols,
                                                   int* __restrict__ degs) {
    __shared__ int scol[SCOL_CAP];
    __shared__ int deg[BNODES];
    __shared__ int loffs[BNODES];
    __shared__ int fill[BNODES];
    const int tid = threadIdx.x;
    const int b = blockIdx.x;

    if (tid < BNODES) { deg[tid] = 0; fill[tid] = 0; }
    __syncthreads();

    const int beg = goffs[b * PBLK] + boff[b >> 1];
    int end = (b == NB - 1) ? NE : goffs[(b + 1) * PBLK] + boff[(b + 1) >> 1];
    if (end - beg > SCOL_CAP) end = beg + SCOL_CAP;

    int pv[8];
    int npv = 0;
    for (int i = beg + tid; i < end; i += 256) {
        const int v = pairs[i];
        pv[npv++] = v;
        atomicAdd(&deg[v & (BNODES - 1)], 1);
    }
    __syncthreads();

    if (tid < BNODES) {
        const int v = deg[tid];
        int inc = v;
#pragma unroll
        for (int s = 1; s < 64; s <<= 1) {
            int t = __shfl_up(inc, s, 64);
            if (tid >= s) inc += t;
        }
        loffs[tid] = inc;
    }
    __syncthreads();

    for (int j = 0; j < npv; ++j) {
        const int v = pv[j];
        const int dl = v & (BNODES - 1);
        const int pos = (loffs[dl] - deg[dl]) + atomicAdd(&fill[dl], 1);
        scol[pos] = v >> 6;
    }
    __syncthreads();

    // coalesced write-out of the sorted bucket + its degree row
    const int ne = end - beg;
    for (int i = tid; i < ne; i += 256) scols[beg + i] = scol[i];
    if (tid < BNODES) degs[b * BNODES + tid] = deg[tid];
}

// ---------------- pass B: 2-edge-per-instr fp8 gather + fused epilogue -------------
// fp8 rows are 64B; each lane loads uint4 (16B), so 4 lanes cover one row and an
// 8-lane group fetches TWO edges per vmem instruction (lanes 0-3 edge e, 4-7 edge
// e+1) -> divergent vmem instructions halve (the invariant all prior nulls share).
// Lane accumulates 16 channels; node end: one shfl_xor(4) parity exchange.
template<bool POOL>
__global__ __launch_bounds__(256) void spmm_sorted(const int* __restrict__ goffs,
                                                   const int* __restrict__ boff,
                                                   const int* __restrict__ scols,
                                                   const int* __restrict__ degs,
                                                   const uchar* __restrict__ Yl8,
                                                   const ushort* __restrict__ Yr,
                                                   const float* __restrict__ bias,
                                                   const float* __restrict__ bng,
                                                   const float* __restrict__ bnb,
                                                   const float* __restrict__ bnm,
                                                   const float* __restrict__ bnv,
                                                   ushort* __restrict__ outp,
                                                   const int* __restrict__ batch,
                                                   float* __restrict__ gsum,
                                                   float* __restrict__ gcnt) {
    __shared__ int scol[SCOL_CAP];      // 8 KB: dst-sorted src ids
    __shared__ int deg_s[BNODES];
    __shared__ int loffs[BNODES];       // inclusive scan of deg
    __shared__ float pbuf[4][64];       // pool partials (POOL only)
    __shared__ float pcnt[4];
    __shared__ int g0s;
    const int tid = threadIdx.x;
    const int b = blockIdx.x;

    if (POOL) {
        pbuf[tid >> 6][tid & 63] = 0.f;
        if (tid < 4) pcnt[tid] = 0.f;
        if (tid == 0) g0s = batch[b * BNODES];
    }

    const int beg = goffs[b * PBLK] + boff[b >> 1];
    int end = (b == NB - 1) ? NE : goffs[(b + 1) * PBLK] + boff[(b + 1) >> 1];
    if (end - beg > SCOL_CAP) end = beg + SCOL_CAP;
    const int ne = end - beg;

    // coalesced stage of pre-sorted src ids (no atomics, no sort)
    for (int i = tid; i < ne; i += 256) scol[i] = scols[beg + i];
    // degree row + wave-0 inclusive scan
    if (tid < BNODES) {
        const int v = degs[b * BNODES + tid];
        deg_s[tid] = v;
        int inc = v;
#pragma unroll
        for (int s = 1; s < 64; s <<= 1) {
            int t = __shfl_up(inc, s, 64);
            if (tid >= s) inc += t;
        }
        loffs[tid] = inc;
    }
    __syncthreads();

    // phase 4: gather. 8-lane group owns a node; lane = (par = subl>>2, q = subl&3).
    // lane loads 16B (channels q*16..q*16+15) of edge e+par.
    const int wv = tid >> 6, lane = tid & 63;
    const int grp = lane >> 3, subl = lane & 7;
    const int par = subl >> 2;          // which of the 2 edges per batch
    const int q16 = (subl & 3) * 16;    // channel-byte base within row
    const int ch0 = q16 + par * 8;      // this lane's 8 output channels

    float biasj[8], scj[8], mj[8], bbj[8];
#pragma unroll
    for (int j = 0; j < 8; ++j) {
        const int ch = ch0 + j;
        biasj[j] = bias[ch];
        scj[j] = bng[ch] * rsqrtf(bnv[ch] + BN_EPS);
        mj[j] = bnm[ch];
        bbj[j] = bnb[ch];
    }

    for (int i = 0; i < 2; ++i) {
        const int nl = wv * 16 + i * 8 + grp;
        const int node = b * BNODES + nl;
        if (node >= NN) continue;
        const int dg = deg_s[nl];
        const int nbeg = loffs[nl] - dg;
        const int nend = nbeg + dg;
        float a16[16], c16[16];
#pragma unroll
        for (int j = 0; j < 16; ++j) { a16[j] = 0.f; c16[j] = 0.f; }
        int e = nbeg;
        // 4 loads in flight = 8 edges per iteration
        for (; e + 7 < nend; e += 8) {
            const int s0 = scol[e + par];
            const int s1 = scol[e + 2 + par];
            const int s2 = scol[e + 4 + par];
            const int s3 = scol[e + 6 + par];
            const uint4 r0 = *(const uint4*)(Yl8 + (size_t)s0 * 64 + q16);
            const uint4 r1 = *(const uint4*)(Yl8 + (size_t)s1 * 64 + q16);
            const uint4 r2 = *(const uint4*)(Yl8 + (size_t)s2 * 64 + q16);
            const uint4 r3 = *(const uint4*)(Yl8 + (size_t)s3 * 64 + q16);
            accf8x16(a16, r0); accf8x16(c16, r1); accf8x16(a16, r2); accf8x16(c16, r3);
        }
        for (; e + 1 < nend; e += 2) {
            const int s0 = scol[e + par];
            const uint4 r0 = *(const uint4*)(Yl8 + (size_t)s0 * 64 + q16);
            accf8x16(a16, r0);
        }
        if (e < nend && par == 0) {     // odd remainder: parity-0 lanes only
            const int s0 = scol[e];
            const uint4 r0 = *(const uint4*)(Yl8 + (size_t)s0 * 64 + q16);
            accf8x16(a16, r0);
        }
        // merge ILP sets, then parity exchange: lane keeps its own 8 channels
        // (offset par*8 within its 16) and receives the partner's other 8.
#pragma unroll
        for (int j = 0; j < 16; ++j) a16[j] += c16[j];
        float ho[8];
#pragma unroll
        for (int j = 0; j < 8; ++j) {
            const float send = par ? a16[j] : a16[8 + j];
            const float keep = par ? a16[8 + j] : a16[j];
            ho[j] = keep + __shfl_xor(send, 4, 64);
        }
        const float inv = 1.0f / fmaxf((float)dg, 1.0f);
        const uint4 yr = *(const uint4*)(Yr + (size_t)node * 64 + ch0);
        float hj[8];
        hj[0] = ho[0] * inv + biasj[0] + blo(yr.x);
        hj[1] = ho[1] * inv + biasj[1] + bhi(yr.x);
        hj[2] = ho[2] * inv + biasj[2] + blo(yr.y);
        hj[3] = ho[3] * inv + biasj[3] + bhi(yr.y);
        hj[4] = ho[4] * inv + biasj[4] + blo(yr.z);
        hj[5] = ho[5] * inv + biasj[5] + bhi(yr.z);
        hj[6] = ho[6] * inv + biasj[6] + blo(yr.w);
        hj[7] = ho[7] * inv + biasj[7] + bhi(yr.w);
        float o[8];
#pragma unroll
        for (int j = 0; j < 8; ++j)
            o[j] = fmaxf((hj[j] - mj[j]) * scj[j] + bbj[j], 0.0f);
        if (!POOL) {
            unsigned ow[4];
#pragma unroll
            for (int j = 0; j < 4; ++j)
                ow[j] = (unsigned)f2b(o[2 * j]) | ((unsigned)f2b(o[2 * j + 1]) << 16);
            uint4 ov;
            ov.x = ow[0]; ov.y = ow[1]; ov.z = ow[2]; ov.w = ow[3];
            *(uint4*)(outp + (size_t)node * 64 + ch0) = ov;
        } else {
            const int g = batch[node];
            const int gi = g - g0s;
            if (gi < 4) {
#pragma unroll
                for (int j = 0; j < 8; ++j) atomicAdd(&pbuf[gi][ch0 + j], o[j]);
                if (subl == 0) atomicAdd(&pcnt[gi], 1.0f);
            } else {   // span > 4 graphs in one block: direct (rare/never)
#pragma unroll
                for (int j = 0; j < 8; ++j) atomicAdd(&gsum[g * 64 + ch0 + j], o[j]);
                if (subl == 0) atomicAdd(&gcnt[g], 1.0f);
            }
        }
    }
    if (POOL) {
        __syncthreads();
        const int q = tid >> 6, ch = tid & 63;
        const int g = g0s + q;
        if (g < GG) {
            const float v = pbuf[q][ch];
            if (v != 0.f) atomicAdd(&gsum[g * 64 + ch], v);
        }
        if (tid < 4) {
            const int gq = g0s + tid;
            if (gq < GG && pcnt[tid] > 0.f) atomicAdd(&gcnt[gq], pcnt[tid]);
        }
    }
}

// ---------------- classifier head ----------------
__global__ __launch_bounds__(64) void head_kernel(const float* __restrict__ gsum,
                                                  const float* __restrict__ gcnt,
                                                  const float* __restrict__ Wc1,
                                                  const float* __restrict__ bc1,
                                                  const float* __restrict__ g3,
                                                  const float* __restrict__ b3,
                                                  const float* __restrict__ m3,
                                                  const float* __restrict__ v3,
                                                  const float* __restrict__ Wc2,
                                                  const float* __restrict__ bc2,
                                                  float* __restrict__ out) {
    __shared__ float sg[64];
    __shared__ float st[64];
    __shared__ float sl[10];
    __shared__ float sls;
    const int b = blockIdx.x;
    const int c = threadIdx.x;
    sg[c] = gsum[b * 64 + c] / fmaxf(gcnt[b], 1.0f);
    __syncthreads();
    float acc = bc1[c];
#pragma unroll
    for (int k = 0; k < 64; ++k) acc += sg[k] * Wc1[k * 64 + c];
    const float sc = g3[c] * rsqrtf(v3[c] + BN_EPS);
    st[c] = fmaxf((acc - m3[c]) * sc + b3[c], 0.0f);
    __syncthreads();
    if (c < CC) {
        float lg = bc2[c];
#pragma unroll
        for (int k = 0; k < 64; ++k) lg += st[k] * Wc2[k * CC + c];
        sl[c] = lg;
    }
    __syncthreads();
    if (c == 0) {
        float mx = sl[0];
        for (int i = 1; i < CC; ++i) mx = fmaxf(mx, sl[i]);
        float s = 0.f;
        for (int i = 0; i < CC; ++i) s += expf(sl[i] - mx);
        sls = mx + logf(s);
    }
    __syncthreads();
    if (c < CC) out[b * CC + c] = sl[c] - sls;
}

extern "C" void kernel_launch(void* const* d_in, const int* in_sizes, int n_in,
                              void* d_out, int out_size, void* d_ws, size_t ws_size,
                              hipStream_t stream) {
    const float* x    = (const float*)d_in[0];
    const int*   ei   = (const int*)d_in[1];
    const int*   batch= (const int*)d_in[2];
    const float* W1l  = (const float*)d_in[3];
    const float* W1r  = (const float*)d_in[4];
    const float* b1   = (const float*)d_in[5];
    const float* W2l  = (const float*)d_in[6];
    const float* W2r  = (const float*)d_in[7];
    const float* b2   = (const float*)d_in[8];
    const float* bn1g = (const float*)d_in[9];
    const float* bn1b = (const float*)d_in[10];
    const float* bn1m = (const float*)d_in[11];
    const float* bn1v = (const float*)d_in[12];
    const float* bn2g = (const float*)d_in[13];
    const float* bn2b = (const float*)d_in[14];
    const float* bn2m = (const float*)d_in[15];
    const float* bn2v = (const float*)d_in[16];
    const float* bn3g = (const float*)d_in[17];
    const float* bn3b = (const float*)d_in[18];
    const float* bn3m = (const float*)d_in[19];
    const float* bn3v = (const float*)d_in[20];
    const float* Wc1  = (const float*)d_in[21];
    const float* bc1  = (const float*)d_in[22];
    const float* Wc2  = (const float*)d_in[23];
    const float* bc2  = (const float*)d_in[24];
    float* out = (float*)d_out;

    const int* src = ei;
    const int* dst = ei + NE;

    // workspace layout (all blocks 16B-aligned)
    char* p = (char*)d_ws;
    uchar*  yl8  = (uchar*)p;                  p += (size_t)NN * 64;            // 6.4 MB (fp8)
    ushort* yr   = (ushort*)p;                 p += (size_t)NN * 64 * 2;        // 12.8 MB
    ushort* hbuf = (ushort*)p;                 p += (size_t)NN * 64 * 2;        // 12.8 MB
    int*    pairs= (int*)p;                    p += (size_t)NE * 4;             // 6.4 MB
    int*    scols= (int*)p;                    p += (size_t)NE * 4;             // 6.4 MB
    int*    degs = (int*)p;                    p += (size_t)NB * BNODES * 4;    // 400 KB
    int*    hist = (int*)p;                    p += (size_t)MHIST * 4;          // 800 KB
    int*    goffs= (int*)p;                    p += (size_t)MHIST * 4;          // 800 KB
    int*    bsum = (int*)p;                    p += 1024 * 4;
    int*    boff = (int*)p;                    p += 1024 * 4;
    ushort* w1ls = (ushort*)p;                 p += (size_t)FF * 64 * 2;
    ushort* w1rs = (ushort*)p;                 p += (size_t)FF * 64 * 2;
    ushort* w2ls = (ushort*)p;                 p += (size_t)HH * 64 * 2;
    ushort* w2rs = (ushort*)p;                 p += (size_t)HH * 64 * 2;
    float* gsum  = (float*)p;                  p += (size_t)GG * 64 * 4;        // gsum+gcnt
    float* gcnt  = gsum + GG * 64;             p += (size_t)GG * 4;             //  contiguous

    // ---- edge counting sort (once, reused by both layers) + fused prep ----
    edge_hist<<<PBLK + 2, 1024, 0, stream>>>(dst, hist, W1l, W1r, W2l, W2r,
                                             w1ls, w1rs, w2ls, w2rs, gsum);
    scan_block<<<NSCAN, 256, 0, stream>>>(hist, goffs, bsum);
    scan_bsums<<<1, 256, 0, stream>>>(bsum, boff);
    edge_scatter<<<PBLK, 1024, 0, stream>>>(src, dst, hist, goffs, boff, pairs);
    bucket_sort<<<NB, 256, 0, stream>>>(goffs, boff, pairs, scols, degs);

    // ---- layer 1 ----
    gemm_mfma<FF, 2, true><<<1563, 256, 0, stream>>>((const void*)x, w1ls, w1rs, yl8, yr);
    spmm_sorted<false><<<NB, 256, 0, stream>>>(goffs, boff, scols, degs, yl8, yr, b1,
                                               bn1g, bn1b, bn1m, bn1v, hbuf,
                                               batch, gsum, gcnt);

    // ---- layer 2 (pool fused into spmm epilogue; no h write) ----
    gemm_mfma<HH, 2, false><<<1563, 256, 0, stream>>>((const void*)hbuf, w2ls, w2rs, yl8, yr);
    spmm_sorted<true><<<NB, 256, 0, stream>>>(goffs, boff, scols, degs, yl8, yr, b2,
                                              bn2g, bn2b, bn2m, bn2v, hbuf,
                                              batch, gsum, gcnt);

    // ---- head ----
    head_kernel<<<GG, 64, 0, stream>>>(gsum, gcnt, Wc1, bc1,
                                       bn3g, bn3b, bn3m, bn3v, Wc2, bc2, out);
}